// Round 3
// baseline (186.695 us; speedup 1.0000x reference)
//
#include <hip/hip_runtime.h>
#include <math.h>

// Problem constants (match reference)
#define B_SZ   4096
#define NMAX_SZ 64
#define H_SZ   768      // = 64 lanes * 12
#define Q_SZ   16384
#define S_SZ   256

// ---------------------------------------------------------------------------
// helpers
// ---------------------------------------------------------------------------
__device__ __forceinline__ float dot12(const float4 a0, const float4 a1, const float4 a2,
                                       const float4 b0, const float4 b1, const float4 b2) {
  float p = a0.x * b0.x + a0.y * b0.y + a0.z * b0.z + a0.w * b0.w;
  p += a1.x * b1.x + a1.y * b1.y + a1.z * b1.z + a1.w * b1.w;
  p += a2.x * b2.x + a2.y * b2.y + a2.z * b2.z + a2.w * b2.w;
  return p;
}

__device__ __forceinline__ void upd4(float4& a, const float c, const float e, const float4 x) {
  a.x = fmaf(e, x.x, a.x * c);
  a.y = fmaf(e, x.y, a.y * c);
  a.z = fmaf(e, x.z, a.z * c);
  a.w = fmaf(e, x.w, a.w * c);
}

__device__ __forceinline__ float4 comb4(const float4 a, const float ca,
                                        const float4 b, const float cb, const float inv) {
  float4 r;
  r.x = (a.x * ca + b.x * cb) * inv;
  r.y = (a.y * ca + b.y * cb) * inv;
  r.z = (a.z * ca + b.z * cb) * inv;
  r.w = (a.w * ca + b.w * cb) * inv;
  return r;
}

__device__ __forceinline__ float wave_sum(float p) {
#pragma unroll
  for (int off = 32; off > 0; off >>= 1) p += __shfl_xor(p, off);
  return p;
}

// ---------------------------------------------------------------------------
// Kernel 1: fused attention-pool, persistent waves + dynamic work queue.
// Each WAVE grabs a b from an atomic counter and pools it (no LDS/barriers).
// Lane owns h = 12*lane .. +11 (3 x float4); dual online-softmax chains
// (even/odd rows) + register prefetch. Epilogue: d1[b]=emb.wm_w[:H],
// d2[b]=emb.wm_w[H:] while emb is in registers.
// Grid = 1024 blocks (exactly resident at 4 blocks/CU); the queue drains
// with every wave busy -> immune to len[b] variance (was 62% efficiency).
// ---------------------------------------------------------------------------
__global__ __launch_bounds__(256, 4) void merge_dots_kernel(
    const float* __restrict__ padded, const float* __restrict__ qw,
    const float* __restrict__ qb, const float* __restrict__ wmw,
    const int* __restrict__ lengths, int* __restrict__ counter,
    float* __restrict__ d1, float* __restrict__ d2) {
  const int t = threadIdx.x;
  const int lane = t & 63;
  const int h0 = 12 * lane;
  const float qb0 = qb[0];

  const float4* qwp = (const float4*)(qw + h0);
  const float4 q0 = qwp[0], q1 = qwp[1], q2 = qwp[2];
  const float4* w1p = (const float4*)(wmw + h0);
  const float4* w2p = (const float4*)(wmw + H_SZ + h0);
  const float4 w10 = w1p[0], w11 = w1p[1], w12 = w1p[2];
  const float4 w20 = w2p[0], w21 = w2p[1], w22 = w2p[2];

  for (;;) {
    int b;
    if (lane == 0) b = atomicAdd(counter, 1);
    b = __shfl(b, 0);
    if (b >= B_SZ) return;

    const int len = lengths[b];
    const float* base = padded + (size_t)b * (NMAX_SZ * H_SZ) + h0;

    // two online-softmax chains (A: even rows, B: odd rows)
    float mA = -INFINITY, lA = 0.f, mB = -INFINITY, lB = 0.f;
    float4 aA0 = {0, 0, 0, 0}, aA1 = {0, 0, 0, 0}, aA2 = {0, 0, 0, 0};
    float4 aB0 = {0, 0, 0, 0}, aB1 = {0, 0, 0, 0}, aB2 = {0, 0, 0, 0};

    // current pair (row 0 always valid; row 1 clamped if len==1)
    const float4* rA = (const float4*)(base);
    const float4* rB = (const float4*)(base + ((1 < len) ? 1 : 0) * H_SZ);
    float4 cA0 = rA[0], cA1 = rA[1], cA2 = rA[2];
    float4 cB0 = rB[0], cB1 = rB[1], cB2 = rB[2];

    for (int n = 0; n < len; n += 2) {
      // prefetch next pair (clamped addresses stay in-range; tail hits L1)
      const int pA = (n + 2 < len) ? n + 2 : len - 1;
      const int pB = (n + 3 < len) ? n + 3 : len - 1;
      const float4* fA = (const float4*)(base + pA * H_SZ);
      const float4* fB = (const float4*)(base + pB * H_SZ);
      const float4 nA0 = fA[0], nA1 = fA[1], nA2 = fA[2];
      const float4 nB0 = fB[0], nB1 = fB[1], nB2 = fB[2];

      // chain A: row n
      {
        const float sA = wave_sum(dot12(cA0, cA1, cA2, q0, q1, q2)) + qb0;
        const float mn = fmaxf(mA, sA);
        const float c = __expf(mA - mn);  // first iter: exp(-inf)=0
        const float e = __expf(sA - mn);
        lA = lA * c + e;
        upd4(aA0, c, e, cA0); upd4(aA1, c, e, cA1); upd4(aA2, c, e, cA2);
        mA = mn;
      }
      // chain B: row n+1 (uniform branch per wave)
      if (n + 1 < len) {
        const float sB = wave_sum(dot12(cB0, cB1, cB2, q0, q1, q2)) + qb0;
        const float mn = fmaxf(mB, sB);
        const float c = __expf(mB - mn);
        const float e = __expf(sB - mn);
        lB = lB * c + e;
        upd4(aB0, c, e, cB0); upd4(aB1, c, e, cB1); upd4(aB2, c, e, cB2);
        mB = mn;
      }
      cA0 = nA0; cA1 = nA1; cA2 = nA2;
      cB0 = nB0; cB1 = nB1; cB2 = nB2;
    }

    // merge chains (len==1: mB=-inf -> cB=0, contributes nothing)
    const float M = fmaxf(mA, mB);
    const float cA = __expf(mA - M), cB = __expf(mB - M);
    const float L = lA * cA + lB * cB;
    const float inv = 1.f / L;
    const float4 e0 = comb4(aA0, cA, aB0, cB, inv);
    const float4 e1 = comb4(aA1, cA, aB1, cB, inv);
    const float4 e2 = comb4(aA2, cA, aB2, cB, inv);

    // epilogue: dots with both wm_w halves while emb is in registers
    float p1 = dot12(e0, e1, e2, w10, w11, w12);
    float p2 = dot12(e0, e1, e2, w20, w21, w22);
#pragma unroll
    for (int off = 32; off > 0; off >>= 1) {
      p1 += __shfl_xor(p1, off);
      p2 += __shfl_xor(p2, off);
    }
    if (lane == 0) {
      d1[b] = p1;
      d2[b] = p2;
    }
  }
}

// ---------------------------------------------------------------------------
// Kernel 2: logits[q] = (d1[cni[npt[q]]] + d2[npi[q]] + wm_b) / TEMP ; pos flag
// ---------------------------------------------------------------------------
__global__ __launch_bounds__(256) void logits_kernel(
    const float* __restrict__ d1, const float* __restrict__ d2,
    const float* __restrict__ wmb,
    const int* __restrict__ npi, const int* __restrict__ cni,
    const int* __restrict__ npt, const int* __restrict__ labels,
    float* __restrict__ logits, int* __restrict__ pos) {
  const int q = blockIdx.x * 256 + threadIdx.x;
  if (q >= Q_SZ) return;
  const int ty = npt[q];
  const float sims = d1[cni[ty]] + d2[npi[q]] + wmb[0];
  logits[q] = sims / 0.1f;            // match reference's division by TEMP
  pos[q] = (labels[q] == 1) ? 1 : 0;  // labels is [Q,1]
}

// ---------------------------------------------------------------------------
// Kernel 3: per-segment LSE terms. One block per segment s; scans all Q
// (logits/npt/pos are L2-resident). Two passes: max, then sums.
// ---------------------------------------------------------------------------
__global__ __launch_bounds__(256) void segment_kernel(
    const float* __restrict__ logits, const int* __restrict__ npt,
    const int* __restrict__ pos,
    float* __restrict__ seg_term, float* __restrict__ seg_has) {
  const int s = blockIdx.x;
  const int t = threadIdx.x;
  const int lane = t & 63, wid = t >> 6;
  __shared__ float rg[4], rp[4], sa4[4], sp4[4], cp4[4];

  float gmax = -INFINITY, pmax = -INFINITY;
  for (int q = t; q < Q_SZ; q += 256) {
    if (npt[q] == s) {
      const float lg = logits[q];
      gmax = fmaxf(gmax, lg);
      if (pos[q]) pmax = fmaxf(pmax, lg);
    }
  }
#pragma unroll
  for (int off = 32; off > 0; off >>= 1) {
    gmax = fmaxf(gmax, __shfl_xor(gmax, off));
    pmax = fmaxf(pmax, __shfl_xor(pmax, off));
  }
  if (lane == 0) { rg[wid] = gmax; rp[wid] = pmax; }
  __syncthreads();
  gmax = fmaxf(fmaxf(rg[0], rg[1]), fmaxf(rg[2], rg[3]));
  pmax = fmaxf(fmaxf(rp[0], rp[1]), fmaxf(rp[2], rp[3]));
  const float gmaxs = (gmax == -INFINITY) ? 0.f : gmax;
  const float pmaxs = (pmax == -INFINITY) ? 0.f : pmax;

  float sa = 0.f, sp = 0.f, cnt = 0.f;
  for (int q = t; q < Q_SZ; q += 256) {
    if (npt[q] == s) {
      const float lg = logits[q];
      sa += expf(lg - gmaxs);
      if (pos[q]) { sp += expf(lg - pmaxs); cnt += 1.f; }
    }
  }
#pragma unroll
  for (int off = 32; off > 0; off >>= 1) {
    sa += __shfl_xor(sa, off);
    sp += __shfl_xor(sp, off);
    cnt += __shfl_xor(cnt, off);
  }
  if (lane == 0) { sa4[wid] = sa; sp4[wid] = sp; cp4[wid] = cnt; }
  __syncthreads();
  if (t == 0) {
    sa = sa4[0] + sa4[1] + sa4[2] + sa4[3];
    sp = sp4[0] + sp4[1] + sp4[2] + sp4[3];
    cnt = cp4[0] + cp4[1] + cp4[2] + cp4[3];
    const bool haspos = cnt > 0.f;
    float term = 0.f;
    if (haspos) term = (logf(sa) + gmaxs) - (logf(sp) + pmaxs);
    seg_term[s] = term;
    seg_has[s] = haspos ? 1.f : 0.f;
  }
}

// ---------------------------------------------------------------------------
// Kernel 4: loss = sum(term) / max(sum(has), 1)
// ---------------------------------------------------------------------------
__global__ __launch_bounds__(256) void finalize_kernel(
    const float* __restrict__ seg_term, const float* __restrict__ seg_has,
    float* __restrict__ out) {
  const int t = threadIdx.x;
  const int lane = t & 63, wid = t >> 6;
  __shared__ float rt[4], rh[4];
  float v = seg_term[t];
  float h = seg_has[t];
#pragma unroll
  for (int off = 32; off > 0; off >>= 1) {
    v += __shfl_xor(v, off);
    h += __shfl_xor(h, off);
  }
  if (lane == 0) { rt[wid] = v; rh[wid] = h; }
  __syncthreads();
  if (t == 0) {
    const float total = rt[0] + rt[1] + rt[2] + rt[3];
    const float nv = rh[0] + rh[1] + rh[2] + rh[3];
    out[0] = total / fmaxf(nv, 1.f);
  }
}

extern "C" void kernel_launch(void* const* d_in, const int* in_sizes, int n_in,
                              void* d_out, int out_size, void* d_ws, size_t ws_size,
                              hipStream_t stream) {
  const float* padded  = (const float*)d_in[0];
  const float* qw      = (const float*)d_in[1];
  const float* qb      = (const float*)d_in[2];
  const float* wmw     = (const float*)d_in[3];
  const float* wmb     = (const float*)d_in[4];
  const int*   lengths = (const int*)d_in[5];
  const int*   npi     = (const int*)d_in[6];
  const int*   cni     = (const int*)d_in[7];
  const int*   npt     = (const int*)d_in[8];
  const int*   labels  = (const int*)d_in[9];
  float* out = (float*)d_out;

  // workspace layout (all fully written before read each call)
  float* d1       = (float*)d_ws;          // B
  float* d2       = d1 + B_SZ;             // B
  float* logits   = d2 + B_SZ;             // Q
  int*   pos      = (int*)(logits + Q_SZ); // Q
  float* seg_term = (float*)(pos + Q_SZ);  // S
  float* seg_has  = seg_term + S_SZ;       // S
  int*   counter  = (int*)(seg_has + S_SZ);// 1 (work-queue head)

  hipMemsetAsync(counter, 0, sizeof(int), stream);  // graph-capture-safe
  merge_dots_kernel<<<B_SZ / 4, 256, 0, stream>>>(padded, qw, qb, wmw, lengths,
                                                  counter, d1, d2);
  logits_kernel<<<Q_SZ / 256, 256, 0, stream>>>(d1, d2, wmb, npi, cni, npt, labels,
                                                logits, pos);
  segment_kernel<<<S_SZ, 256, 0, stream>>>(logits, npt, pos, seg_term, seg_has);
  finalize_kernel<<<1, 256, 0, stream>>>(seg_term, seg_has, out);
}

// Round 4
// 114.772 us; speedup vs baseline: 1.6267x; 1.6267x over previous
//
#include <hip/hip_runtime.h>
#include <math.h>

// Problem constants (match reference)
#define B_SZ   4096
#define NMAX_SZ 64
#define H_SZ   768      // = 64 lanes * 12
#define Q_SZ   16384
#define S_SZ   256

// ---------------------------------------------------------------------------
// helpers
// ---------------------------------------------------------------------------
__device__ __forceinline__ float dot12(const float4 a0, const float4 a1, const float4 a2,
                                       const float4 b0, const float4 b1, const float4 b2) {
  float p = a0.x * b0.x + a0.y * b0.y + a0.z * b0.z + a0.w * b0.w;
  p += a1.x * b1.x + a1.y * b1.y + a1.z * b1.z + a1.w * b1.w;
  p += a2.x * b2.x + a2.y * b2.y + a2.z * b2.z + a2.w * b2.w;
  return p;
}

__device__ __forceinline__ void upd4(float4& a, const float c, const float e, const float4 x) {
  a.x = fmaf(e, x.x, a.x * c);
  a.y = fmaf(e, x.y, a.y * c);
  a.z = fmaf(e, x.z, a.z * c);
  a.w = fmaf(e, x.w, a.w * c);
}

__device__ __forceinline__ float wave_sum(float p) {
#pragma unroll
  for (int off = 32; off > 0; off >>= 1) p += __shfl_xor(p, off);
  return p;
}

// ---------------------------------------------------------------------------
// Kernel 1: fused attention-pool. ONE BLOCK PER b (4096 blocks, 4x the
// resident capacity -> HW dispatcher backfills, smoothing len[b] variance).
// Wave w handles rows n = w, w+4, w+8, ... with the barrier-free wave-local
// pipeline (float4 loads, dual online-softmax chains, register prefetch).
// One LDS merge (transposed [i][w][lane] layout, conflict-free) + one
// __syncthreads combines the 4 partial states; wave 0 runs the wm_w epilogue.
// No atomics. Outputs d1[b]=emb.wm_w[:H], d2[b]=emb.wm_w[H:].
// ---------------------------------------------------------------------------
__global__ __launch_bounds__(256, 4) void merge_dots_kernel(
    const float* __restrict__ padded, const float* __restrict__ qw,
    const float* __restrict__ qb, const float* __restrict__ wmw,
    const int* __restrict__ lengths,
    float* __restrict__ d1, float* __restrict__ d2) {
  const int b = blockIdx.x;
  const int t = threadIdx.x;
  const int lane = t & 63;
  const int w = t >> 6;
  const int len = lengths[b];
  const int h0 = 12 * lane;

  __shared__ float sm[4], sl[4];
  __shared__ float sa[12 * 4 * 64];  // [i][w][lane], 12 KB, conflict-free

  const float4* qwp = (const float4*)(qw + h0);
  const float4 q0 = qwp[0], q1 = qwp[1], q2 = qwp[2];
  const float qb0 = qb[0];

  const float* base = padded + (size_t)b * (NMAX_SZ * H_SZ) + h0;
  const float* wbase = base + w * H_SZ;          // rows w, w+4, ... stride 4*H
  const int cnt = (len > w) ? ((len - w + 3) >> 2) : 0;

  // wave-partial online-softmax state (unnormalized)
  float m = -INFINITY, l = 0.f;
  float4 a0 = {0, 0, 0, 0}, a1 = {0, 0, 0, 0}, a2 = {0, 0, 0, 0};

  if (cnt > 0) {
    // dual chains over this wave's row list (k indexes rows w+4k)
    float mA = -INFINITY, lA = 0.f, mB = -INFINITY, lB = 0.f;
    float4 aA0 = {0, 0, 0, 0}, aA1 = {0, 0, 0, 0}, aA2 = {0, 0, 0, 0};
    float4 aB0 = {0, 0, 0, 0}, aB1 = {0, 0, 0, 0}, aB2 = {0, 0, 0, 0};

    const float4* rA = (const float4*)(wbase);
    const float4* rB = (const float4*)(wbase + (size_t)((1 < cnt) ? 1 : 0) * 4 * H_SZ);
    float4 cA0 = rA[0], cA1 = rA[1], cA2 = rA[2];
    float4 cB0 = rB[0], cB1 = rB[1], cB2 = rB[2];

    for (int k = 0; k < cnt; k += 2) {
      // prefetch next pair (clamped; tail hits L1)
      const int pA = (k + 2 < cnt) ? k + 2 : cnt - 1;
      const int pB = (k + 3 < cnt) ? k + 3 : cnt - 1;
      const float4* fA = (const float4*)(wbase + (size_t)pA * 4 * H_SZ);
      const float4* fB = (const float4*)(wbase + (size_t)pB * 4 * H_SZ);
      const float4 nA0 = fA[0], nA1 = fA[1], nA2 = fA[2];
      const float4 nB0 = fB[0], nB1 = fB[1], nB2 = fB[2];

      {
        const float sA = wave_sum(dot12(cA0, cA1, cA2, q0, q1, q2)) + qb0;
        const float mn = fmaxf(mA, sA);
        const float c = __expf(mA - mn);  // first iter: exp(-inf)=0
        const float e = __expf(sA - mn);
        lA = lA * c + e;
        upd4(aA0, c, e, cA0); upd4(aA1, c, e, cA1); upd4(aA2, c, e, cA2);
        mA = mn;
      }
      if (k + 1 < cnt) {
        const float sB = wave_sum(dot12(cB0, cB1, cB2, q0, q1, q2)) + qb0;
        const float mn = fmaxf(mB, sB);
        const float c = __expf(mB - mn);
        const float e = __expf(sB - mn);
        lB = lB * c + e;
        upd4(aB0, c, e, cB0); upd4(aB1, c, e, cB1); upd4(aB2, c, e, cB2);
        mB = mn;
      }
      cA0 = nA0; cA1 = nA1; cA2 = nA2;
      cB0 = nB0; cB1 = nB1; cB2 = nB2;
    }

    // merge dual chains (mA finite since chain A owns k=0; mB may be -inf)
    m = fmaxf(mA, mB);
    const float cA = __expf(mA - m), cB = __expf(mB - m);
    l = lA * cA + lB * cB;
    a0.x = aA0.x * cA + aB0.x * cB; a0.y = aA0.y * cA + aB0.y * cB;
    a0.z = aA0.z * cA + aB0.z * cB; a0.w = aA0.w * cA + aB0.w * cB;
    a1.x = aA1.x * cA + aB1.x * cB; a1.y = aA1.y * cA + aB1.y * cB;
    a1.z = aA1.z * cA + aB1.z * cB; a1.w = aA1.w * cA + aB1.w * cB;
    a2.x = aA2.x * cA + aB2.x * cB; a2.y = aA2.y * cA + aB2.y * cB;
    a2.z = aA2.z * cA + aB2.z * cB; a2.w = aA2.w * cA + aB2.w * cB;
  }

  // publish wave-partial state to LDS (transposed: sa[i*256 + w*64 + lane])
  if (lane == 0) { sm[w] = m; sl[w] = l; }
  if (w != 0) {  // wave 0 keeps its state in registers
    const float av[12] = {a0.x, a0.y, a0.z, a0.w, a1.x, a1.y, a1.z, a1.w,
                          a2.x, a2.y, a2.z, a2.w};
#pragma unroll
    for (int i = 0; i < 12; ++i) sa[i * 256 + w * 64 + lane] = av[i];
  }
  __syncthreads();
  if (w != 0) return;

  // wave 0: cross-wave merge (M finite: wave 0 owns row 0)
  const float M = fmaxf(fmaxf(sm[0], sm[1]), fmaxf(sm[2], sm[3]));
  const float c0 = __expf(sm[0] - M), c1 = __expf(sm[1] - M);
  const float c2 = __expf(sm[2] - M), c3 = __expf(sm[3] - M);
  const float L = sl[0] * c0 + sl[1] * c1 + sl[2] * c2 + sl[3] * c3;
  const float inv = 1.f / L;

  float e[12] = {a0.x, a0.y, a0.z, a0.w, a1.x, a1.y, a1.z, a1.w,
                 a2.x, a2.y, a2.z, a2.w};
#pragma unroll
  for (int i = 0; i < 12; ++i) {
    e[i] = (e[i] * c0 + sa[i * 256 + 64 + lane] * c1 +
            sa[i * 256 + 128 + lane] * c2 + sa[i * 256 + 192 + lane] * c3) * inv;
  }

  // epilogue: dots with both wm_w halves
  const float* w1 = wmw + h0;
  const float* w2 = wmw + H_SZ + h0;
  float p1 = 0.f, p2 = 0.f;
#pragma unroll
  for (int i = 0; i < 12; ++i) {
    p1 = fmaf(e[i], w1[i], p1);
    p2 = fmaf(e[i], w2[i], p2);
  }
#pragma unroll
  for (int off = 32; off > 0; off >>= 1) {
    p1 += __shfl_xor(p1, off);
    p2 += __shfl_xor(p2, off);
  }
  if (lane == 0) {
    d1[b] = p1;
    d2[b] = p2;
  }
}

// ---------------------------------------------------------------------------
// Kernel 2: logits[q] = (d1[cni[npt[q]]] + d2[npi[q]] + wm_b) / TEMP ; pos flag
// ---------------------------------------------------------------------------
__global__ __launch_bounds__(256) void logits_kernel(
    const float* __restrict__ d1, const float* __restrict__ d2,
    const float* __restrict__ wmb,
    const int* __restrict__ npi, const int* __restrict__ cni,
    const int* __restrict__ npt, const int* __restrict__ labels,
    float* __restrict__ logits, int* __restrict__ pos) {
  const int q = blockIdx.x * 256 + threadIdx.x;
  if (q >= Q_SZ) return;
  const int ty = npt[q];
  const float sims = d1[cni[ty]] + d2[npi[q]] + wmb[0];
  logits[q] = sims / 0.1f;            // match reference's division by TEMP
  pos[q] = (labels[q] == 1) ? 1 : 0;  // labels is [Q,1]
}

// ---------------------------------------------------------------------------
// Kernel 3: per-segment LSE terms. One block per segment s; scans all Q
// (logits/npt/pos are L2-resident). Two passes: max, then sums.
// ---------------------------------------------------------------------------
__global__ __launch_bounds__(256) void segment_kernel(
    const float* __restrict__ logits, const int* __restrict__ npt,
    const int* __restrict__ pos,
    float* __restrict__ seg_term, float* __restrict__ seg_has) {
  const int s = blockIdx.x;
  const int t = threadIdx.x;
  const int lane = t & 63, wid = t >> 6;
  __shared__ float rg[4], rp[4], sa4[4], sp4[4], cp4[4];

  float gmax = -INFINITY, pmax = -INFINITY;
  for (int q = t; q < Q_SZ; q += 256) {
    if (npt[q] == s) {
      const float lg = logits[q];
      gmax = fmaxf(gmax, lg);
      if (pos[q]) pmax = fmaxf(pmax, lg);
    }
  }
#pragma unroll
  for (int off = 32; off > 0; off >>= 1) {
    gmax = fmaxf(gmax, __shfl_xor(gmax, off));
    pmax = fmaxf(pmax, __shfl_xor(pmax, off));
  }
  if (lane == 0) { rg[wid] = gmax; rp[wid] = pmax; }
  __syncthreads();
  gmax = fmaxf(fmaxf(rg[0], rg[1]), fmaxf(rg[2], rg[3]));
  pmax = fmaxf(fmaxf(rp[0], rp[1]), fmaxf(rp[2], rp[3]));
  const float gmaxs = (gmax == -INFINITY) ? 0.f : gmax;
  const float pmaxs = (pmax == -INFINITY) ? 0.f : pmax;

  float sa = 0.f, sp = 0.f, cnt = 0.f;
  for (int q = t; q < Q_SZ; q += 256) {
    if (npt[q] == s) {
      const float lg = logits[q];
      sa += expf(lg - gmaxs);
      if (pos[q]) { sp += expf(lg - pmaxs); cnt += 1.f; }
    }
  }
#pragma unroll
  for (int off = 32; off > 0; off >>= 1) {
    sa += __shfl_xor(sa, off);
    sp += __shfl_xor(sp, off);
    cnt += __shfl_xor(cnt, off);
  }
  if (lane == 0) { sa4[wid] = sa; sp4[wid] = sp; cp4[wid] = cnt; }
  __syncthreads();
  if (t == 0) {
    sa = sa4[0] + sa4[1] + sa4[2] + sa4[3];
    sp = sp4[0] + sp4[1] + sp4[2] + sp4[3];
    cnt = cp4[0] + cp4[1] + cp4[2] + cp4[3];
    const bool haspos = cnt > 0.f;
    float term = 0.f;
    if (haspos) term = (logf(sa) + gmaxs) - (logf(sp) + pmaxs);
    seg_term[s] = term;
    seg_has[s] = haspos ? 1.f : 0.f;
  }
}

// ---------------------------------------------------------------------------
// Kernel 4: loss = sum(term) / max(sum(has), 1)
// ---------------------------------------------------------------------------
__global__ __launch_bounds__(256) void finalize_kernel(
    const float* __restrict__ seg_term, const float* __restrict__ seg_has,
    float* __restrict__ out) {
  const int t = threadIdx.x;
  const int lane = t & 63, wid = t >> 6;
  __shared__ float rt[4], rh[4];
  float v = seg_term[t];
  float h = seg_has[t];
#pragma unroll
  for (int off = 32; off > 0; off >>= 1) {
    v += __shfl_xor(v, off);
    h += __shfl_xor(h, off);
  }
  if (lane == 0) { rt[wid] = v; rh[wid] = h; }
  __syncthreads();
  if (t == 0) {
    const float total = rt[0] + rt[1] + rt[2] + rt[3];
    const float nv = rh[0] + rh[1] + rh[2] + rh[3];
    out[0] = total / fmaxf(nv, 1.f);
  }
}

extern "C" void kernel_launch(void* const* d_in, const int* in_sizes, int n_in,
                              void* d_out, int out_size, void* d_ws, size_t ws_size,
                              hipStream_t stream) {
  const float* padded  = (const float*)d_in[0];
  const float* qw      = (const float*)d_in[1];
  const float* qb      = (const float*)d_in[2];
  const float* wmw     = (const float*)d_in[3];
  const float* wmb     = (const float*)d_in[4];
  const int*   lengths = (const int*)d_in[5];
  const int*   npi     = (const int*)d_in[6];
  const int*   cni     = (const int*)d_in[7];
  const int*   npt     = (const int*)d_in[8];
  const int*   labels  = (const int*)d_in[9];
  float* out = (float*)d_out;

  // workspace layout (all fully written before read each call)
  float* d1       = (float*)d_ws;          // B
  float* d2       = d1 + B_SZ;             // B
  float* logits   = d2 + B_SZ;             // Q
  int*   pos      = (int*)(logits + Q_SZ); // Q
  float* seg_term = (float*)(pos + Q_SZ);  // S
  float* seg_has  = seg_term + S_SZ;       // S

  merge_dots_kernel<<<B_SZ, 256, 0, stream>>>(padded, qw, qb, wmw, lengths, d1, d2);
  logits_kernel<<<Q_SZ / 256, 256, 0, stream>>>(d1, d2, wmb, npi, cni, npt, labels,
                                                logits, pos);
  segment_kernel<<<S_SZ, 256, 0, stream>>>(logits, npt, pos, seg_term, seg_has);
  finalize_kernel<<<1, 256, 0, stream>>>(seg_term, seg_has, out);
}

// Round 5
// 111.961 us; speedup vs baseline: 1.6675x; 1.0251x over previous
//
#include <hip/hip_runtime.h>
#include <math.h>

// Problem constants (match reference)
#define B_SZ   4096
#define NMAX_SZ 64
#define H_SZ   768      // = 3 chunks of 256 floats; lane owns 4 floats per chunk
#define Q_SZ   16384
#define S_SZ   256

// ---------------------------------------------------------------------------
// helpers
// ---------------------------------------------------------------------------
__device__ __forceinline__ float dot12(const float4 a0, const float4 a1, const float4 a2,
                                       const float4 b0, const float4 b1, const float4 b2) {
  float p = a0.x * b0.x + a0.y * b0.y + a0.z * b0.z + a0.w * b0.w;
  p += a1.x * b1.x + a1.y * b1.y + a1.z * b1.z + a1.w * b1.w;
  p += a2.x * b2.x + a2.y * b2.y + a2.z * b2.z + a2.w * b2.w;
  return p;
}

__device__ __forceinline__ void upd4(float4& a, const float c, const float e, const float4 x) {
  a.x = fmaf(e, x.x, a.x * c);
  a.y = fmaf(e, x.y, a.y * c);
  a.z = fmaf(e, x.z, a.z * c);
  a.w = fmaf(e, x.w, a.w * c);
}

__device__ __forceinline__ float wave_sum(float p) {
#pragma unroll
  for (int off = 32; off > 0; off >>= 1) p += __shfl_xor(p, off);
  return p;
}

// ---------------------------------------------------------------------------
// Kernel 1: fused attention-pool. One block per b (4096 blocks, 4x resident
// capacity -> HW backfill). Wave w handles rows w, w+4, w+8, ...
// COALESCED lane ownership: lane l owns floats {4l..4l+3} of each of the
// three 256-float chunks of a row -> every global_load_dwordx4 is a 1 KB
// contiguous burst (16 cachelines), vs the previous stride-48 gather that
// touched 48 lines/instr (3.9 TB/s ceiling). Ownership permutation is
// transparent: all fragment uses end in wave-wide reductions.
// Dual online-softmax chains + register prefetch; one LDS merge + one
// __syncthreads; wave 0 runs the wm_w epilogue.
// Outputs d1[b]=emb.wm_w[:H], d2[b]=emb.wm_w[H:].
// ---------------------------------------------------------------------------
__global__ __launch_bounds__(256, 4) void merge_dots_kernel(
    const float* __restrict__ padded, const float* __restrict__ qw,
    const float* __restrict__ qb, const float* __restrict__ wmw,
    const int* __restrict__ lengths,
    float* __restrict__ d1, float* __restrict__ d2) {
  const int b = blockIdx.x;
  const int t = threadIdx.x;
  const int lane = t & 63;
  const int w = t >> 6;
  const int len = lengths[b];
  const int o0 = 4 * lane;        // chunk 0 offset
  const int o1 = 256 + 4 * lane;  // chunk 1 offset
  const int o2 = 512 + 4 * lane;  // chunk 2 offset

  __shared__ float sm[4], sl[4];
  __shared__ float sa[12 * 4 * 64];  // [i][w][lane], 12 KB, conflict-free

  const float4 q0 = *(const float4*)(qw + o0);
  const float4 q1 = *(const float4*)(qw + o1);
  const float4 q2 = *(const float4*)(qw + o2);
  const float qb0 = qb[0];

  const float* base = padded + (size_t)b * (NMAX_SZ * H_SZ);
  const float* wbase = base + w * H_SZ;          // rows w, w+4, ... stride 4*H
  const int cnt = (len > w) ? ((len - w + 3) >> 2) : 0;

  // wave-partial online-softmax state (unnormalized)
  float m = -INFINITY, l = 0.f;
  float4 a0 = {0, 0, 0, 0}, a1 = {0, 0, 0, 0}, a2 = {0, 0, 0, 0};

  if (cnt > 0) {
    // dual chains over this wave's row list (k indexes rows w+4k)
    float mA = -INFINITY, lA = 0.f, mB = -INFINITY, lB = 0.f;
    float4 aA0 = {0, 0, 0, 0}, aA1 = {0, 0, 0, 0}, aA2 = {0, 0, 0, 0};
    float4 aB0 = {0, 0, 0, 0}, aB1 = {0, 0, 0, 0}, aB2 = {0, 0, 0, 0};

    const float* rA = wbase;
    const float* rB = wbase + (size_t)((1 < cnt) ? 1 : 0) * 4 * H_SZ;
    float4 cA0 = *(const float4*)(rA + o0);
    float4 cA1 = *(const float4*)(rA + o1);
    float4 cA2 = *(const float4*)(rA + o2);
    float4 cB0 = *(const float4*)(rB + o0);
    float4 cB1 = *(const float4*)(rB + o1);
    float4 cB2 = *(const float4*)(rB + o2);

    for (int k = 0; k < cnt; k += 2) {
      // prefetch next pair (clamped; tail hits cache)
      const int pA = (k + 2 < cnt) ? k + 2 : cnt - 1;
      const int pB = (k + 3 < cnt) ? k + 3 : cnt - 1;
      const float* fA = wbase + (size_t)pA * 4 * H_SZ;
      const float* fB = wbase + (size_t)pB * 4 * H_SZ;
      const float4 nA0 = *(const float4*)(fA + o0);
      const float4 nA1 = *(const float4*)(fA + o1);
      const float4 nA2 = *(const float4*)(fA + o2);
      const float4 nB0 = *(const float4*)(fB + o0);
      const float4 nB1 = *(const float4*)(fB + o1);
      const float4 nB2 = *(const float4*)(fB + o2);

      {
        const float sA = wave_sum(dot12(cA0, cA1, cA2, q0, q1, q2)) + qb0;
        const float mn = fmaxf(mA, sA);
        const float c = __expf(mA - mn);  // first iter: exp(-inf)=0
        const float e = __expf(sA - mn);
        lA = lA * c + e;
        upd4(aA0, c, e, cA0); upd4(aA1, c, e, cA1); upd4(aA2, c, e, cA2);
        mA = mn;
      }
      if (k + 1 < cnt) {
        const float sB = wave_sum(dot12(cB0, cB1, cB2, q0, q1, q2)) + qb0;
        const float mn = fmaxf(mB, sB);
        const float c = __expf(mB - mn);
        const float e = __expf(sB - mn);
        lB = lB * c + e;
        upd4(aB0, c, e, cB0); upd4(aB1, c, e, cB1); upd4(aB2, c, e, cB2);
        mB = mn;
      }
      cA0 = nA0; cA1 = nA1; cA2 = nA2;
      cB0 = nB0; cB1 = nB1; cB2 = nB2;
    }

    // merge dual chains (mA finite since chain A owns k=0; mB may be -inf)
    m = fmaxf(mA, mB);
    const float cA = __expf(mA - m), cB = __expf(mB - m);
    l = lA * cA + lB * cB;
    a0.x = aA0.x * cA + aB0.x * cB; a0.y = aA0.y * cA + aB0.y * cB;
    a0.z = aA0.z * cA + aB0.z * cB; a0.w = aA0.w * cA + aB0.w * cB;
    a1.x = aA1.x * cA + aB1.x * cB; a1.y = aA1.y * cA + aB1.y * cB;
    a1.z = aA1.z * cA + aB1.z * cB; a1.w = aA1.w * cA + aB1.w * cB;
    a2.x = aA2.x * cA + aB2.x * cB; a2.y = aA2.y * cA + aB2.y * cB;
    a2.z = aA2.z * cA + aB2.z * cB; a2.w = aA2.w * cA + aB2.w * cB;
  }

  // publish wave-partial state to LDS (transposed: sa[i*256 + w*64 + lane])
  if (lane == 0) { sm[w] = m; sl[w] = l; }
  if (w != 0) {  // wave 0 keeps its state in registers
    const float av[12] = {a0.x, a0.y, a0.z, a0.w, a1.x, a1.y, a1.z, a1.w,
                          a2.x, a2.y, a2.z, a2.w};
#pragma unroll
    for (int i = 0; i < 12; ++i) sa[i * 256 + w * 64 + lane] = av[i];
  }
  __syncthreads();
  if (w != 0) return;

  // wave 0: cross-wave merge (M finite: wave 0 owns row 0)
  const float M = fmaxf(fmaxf(sm[0], sm[1]), fmaxf(sm[2], sm[3]));
  const float c0 = __expf(sm[0] - M), c1 = __expf(sm[1] - M);
  const float c2 = __expf(sm[2] - M), c3 = __expf(sm[3] - M);
  const float L = sl[0] * c0 + sl[1] * c1 + sl[2] * c2 + sl[3] * c3;
  const float inv = 1.f / L;

  float e[12] = {a0.x, a0.y, a0.z, a0.w, a1.x, a1.y, a1.z, a1.w,
                 a2.x, a2.y, a2.z, a2.w};
#pragma unroll
  for (int i = 0; i < 12; ++i) {
    e[i] = (e[i] * c0 + sa[i * 256 + 64 + lane] * c1 +
            sa[i * 256 + 128 + lane] * c2 + sa[i * 256 + 192 + lane] * c3) * inv;
  }

  // epilogue: dots with both wm_w halves (same chunked offsets)
  const float4 w10 = *(const float4*)(wmw + o0);
  const float4 w11 = *(const float4*)(wmw + o1);
  const float4 w12 = *(const float4*)(wmw + o2);
  const float4 w20 = *(const float4*)(wmw + H_SZ + o0);
  const float4 w21 = *(const float4*)(wmw + H_SZ + o1);
  const float4 w22 = *(const float4*)(wmw + H_SZ + o2);
  float p1 = e[0] * w10.x + e[1] * w10.y + e[2] * w10.z + e[3] * w10.w
           + e[4] * w11.x + e[5] * w11.y + e[6] * w11.z + e[7] * w11.w
           + e[8] * w12.x + e[9] * w12.y + e[10] * w12.z + e[11] * w12.w;
  float p2 = e[0] * w20.x + e[1] * w20.y + e[2] * w20.z + e[3] * w20.w
           + e[4] * w21.x + e[5] * w21.y + e[6] * w21.z + e[7] * w21.w
           + e[8] * w22.x + e[9] * w22.y + e[10] * w22.z + e[11] * w22.w;
#pragma unroll
  for (int off = 32; off > 0; off >>= 1) {
    p1 += __shfl_xor(p1, off);
    p2 += __shfl_xor(p2, off);
  }
  if (lane == 0) {
    d1[b] = p1;
    d2[b] = p2;
  }
}

// ---------------------------------------------------------------------------
// Kernel 2: logits[q] = (d1[cni[npt[q]]] + d2[npi[q]] + wm_b) / TEMP ; pos flag
// ---------------------------------------------------------------------------
__global__ __launch_bounds__(256) void logits_kernel(
    const float* __restrict__ d1, const float* __restrict__ d2,
    const float* __restrict__ wmb,
    const int* __restrict__ npi, const int* __restrict__ cni,
    const int* __restrict__ npt, const int* __restrict__ labels,
    float* __restrict__ logits, int* __restrict__ pos) {
  const int q = blockIdx.x * 256 + threadIdx.x;
  if (q >= Q_SZ) return;
  const int ty = npt[q];
  const float sims = d1[cni[ty]] + d2[npi[q]] + wmb[0];
  logits[q] = sims / 0.1f;            // match reference's division by TEMP
  pos[q] = (labels[q] == 1) ? 1 : 0;  // labels is [Q,1]
}

// ---------------------------------------------------------------------------
// Kernel 3: per-segment LSE terms. One block per segment s; scans all Q
// (logits/npt/pos are L2-resident). Two passes: max, then sums.
// ---------------------------------------------------------------------------
__global__ __launch_bounds__(256) void segment_kernel(
    const float* __restrict__ logits, const int* __restrict__ npt,
    const int* __restrict__ pos,
    float* __restrict__ seg_term, float* __restrict__ seg_has) {
  const int s = blockIdx.x;
  const int t = threadIdx.x;
  const int lane = t & 63, wid = t >> 6;
  __shared__ float rg[4], rp[4], sa4[4], sp4[4], cp4[4];

  float gmax = -INFINITY, pmax = -INFINITY;
  for (int q = t; q < Q_SZ; q += 256) {
    if (npt[q] == s) {
      const float lg = logits[q];
      gmax = fmaxf(gmax, lg);
      if (pos[q]) pmax = fmaxf(pmax, lg);
    }
  }
#pragma unroll
  for (int off = 32; off > 0; off >>= 1) {
    gmax = fmaxf(gmax, __shfl_xor(gmax, off));
    pmax = fmaxf(pmax, __shfl_xor(pmax, off));
  }
  if (lane == 0) { rg[wid] = gmax; rp[wid] = pmax; }
  __syncthreads();
  gmax = fmaxf(fmaxf(rg[0], rg[1]), fmaxf(rg[2], rg[3]));
  pmax = fmaxf(fmaxf(rp[0], rp[1]), fmaxf(rp[2], rp[3]));
  const float gmaxs = (gmax == -INFINITY) ? 0.f : gmax;
  const float pmaxs = (pmax == -INFINITY) ? 0.f : pmax;

  float sa = 0.f, sp = 0.f, cnt = 0.f;
  for (int q = t; q < Q_SZ; q += 256) {
    if (npt[q] == s) {
      const float lg = logits[q];
      sa += expf(lg - gmaxs);
      if (pos[q]) { sp += expf(lg - pmaxs); cnt += 1.f; }
    }
  }
#pragma unroll
  for (int off = 32; off > 0; off >>= 1) {
    sa += __shfl_xor(sa, off);
    sp += __shfl_xor(sp, off);
    cnt += __shfl_xor(cnt, off);
  }
  if (lane == 0) { sa4[wid] = sa; sp4[wid] = sp; cp4[wid] = cnt; }
  __syncthreads();
  if (t == 0) {
    sa = sa4[0] + sa4[1] + sa4[2] + sa4[3];
    sp = sp4[0] + sp4[1] + sp4[2] + sp4[3];
    cnt = cp4[0] + cp4[1] + cp4[2] + cp4[3];
    const bool haspos = cnt > 0.f;
    float term = 0.f;
    if (haspos) term = (logf(sa) + gmaxs) - (logf(sp) + pmaxs);
    seg_term[s] = term;
    seg_has[s] = haspos ? 1.f : 0.f;
  }
}

// ---------------------------------------------------------------------------
// Kernel 4: loss = sum(term) / max(sum(has), 1)
// ---------------------------------------------------------------------------
__global__ __launch_bounds__(256) void finalize_kernel(
    const float* __restrict__ seg_term, const float* __restrict__ seg_has,
    float* __restrict__ out) {
  const int t = threadIdx.x;
  const int lane = t & 63, wid = t >> 6;
  __shared__ float rt[4], rh[4];
  float v = seg_term[t];
  float h = seg_has[t];
#pragma unroll
  for (int off = 32; off > 0; off >>= 1) {
    v += __shfl_xor(v, off);
    h += __shfl_xor(h, off);
  }
  if (lane == 0) { rt[wid] = v; rh[wid] = h; }
  __syncthreads();
  if (t == 0) {
    const float total = rt[0] + rt[1] + rt[2] + rt[3];
    const float nv = rh[0] + rh[1] + rh[2] + rh[3];
    out[0] = total / fmaxf(nv, 1.f);
  }
}

extern "C" void kernel_launch(void* const* d_in, const int* in_sizes, int n_in,
                              void* d_out, int out_size, void* d_ws, size_t ws_size,
                              hipStream_t stream) {
  const float* padded  = (const float*)d_in[0];
  const float* qw      = (const float*)d_in[1];
  const float* qb      = (const float*)d_in[2];
  const float* wmw     = (const float*)d_in[3];
  const float* wmb     = (const float*)d_in[4];
  const int*   lengths = (const int*)d_in[5];
  const int*   npi     = (const int*)d_in[6];
  const int*   cni     = (const int*)d_in[7];
  const int*   npt     = (const int*)d_in[8];
  const int*   labels  = (const int*)d_in[9];
  float* out = (float*)d_out;

  // workspace layout (all fully written before read each call)
  float* d1       = (float*)d_ws;          // B
  float* d2       = d1 + B_SZ;             // B
  float* logits   = d2 + B_SZ;             // Q
  int*   pos      = (int*)(logits + Q_SZ); // Q
  float* seg_term = (float*)(pos + Q_SZ);  // S
  float* seg_has  = seg_term + S_SZ;       // S

  merge_dots_kernel<<<B_SZ, 256, 0, stream>>>(padded, qw, qb, wmw, lengths, d1, d2);
  logits_kernel<<<Q_SZ / 256, 256, 0, stream>>>(d1, d2, wmb, npi, cni, npt, labels,
                                                logits, pos);
  segment_kernel<<<S_SZ, 256, 0, stream>>>(logits, npt, pos, seg_term, seg_has);
  finalize_kernel<<<1, 256, 0, stream>>>(seg_term, seg_has, out);
}